// Round 12
// baseline (193.671 us; speedup 1.0000x reference)
//
#include <hip/hip_runtime.h>
#include <stdint.h>

typedef __bf16 bf16_t;
typedef __bf16 bf16x8 __attribute__((ext_vector_type(8)));
typedef float f32x4 __attribute__((ext_vector_type(4)));

#define S_LEN 2048
#define D_MODEL 1024
#define NH 16
#define DKV 64
#define BATCH 2

// 0.125 (1/sqrt(64)) * log2(e): Q pre-scale so softmax runs in exp2 domain.
#define QSCALE 0.1803368801111204f

__device__ __forceinline__ uint16_t f2bfu(float f) {
    union { float f; uint32_t u; } c; c.f = f;
    return (uint16_t)((c.u + 0x7fffu + ((c.u >> 16) & 1u)) >> 16);
}
__device__ __forceinline__ bf16_t f2bf(float f) {
    union { uint16_t s; bf16_t b; } o; o.s = f2bfu(f);
    return o.b;
}
// truncation pack via v_perm: result = (lo>>16) | (hi & 0xFFFF0000)
__device__ __forceinline__ uint32_t pack2t(float lo, float hi) {
    union { float f; uint32_t u; } a, b; a.f = lo; b.f = hi;
    return __builtin_amdgcn_perm(b.u, a.u, 0x07060302);
}
// async global->LDS 16B DMA (dst = wave-uniform base + lane*16)
__device__ __forceinline__ void gld_lds16(const bf16_t* g, bf16_t* l) {
    __builtin_amdgcn_global_load_lds(
        (const __attribute__((address_space(1))) void*)g,
        (__attribute__((address_space(3))) void*)l, 16, 0, 0);
}

// ---------- fp32 -> bf16 convert (x) ----------
__global__ __launch_bounds__(256) void k_convert_x(const float* __restrict__ x,
                                                   bf16_t* __restrict__ xb, int n) {
    int i = (blockIdx.x * 256 + threadIdx.x) * 4;
    if (i < n) {
        float4 v = *(const float4*)(x + i);
        xb[i + 0] = f2bf(v.x);
        xb[i + 1] = f2bf(v.y);
        xb[i + 2] = f2bf(v.z);
        xb[i + 3] = f2bf(v.w);
    }
}

// ---------- transpose + convert all weights in one launch: grid (16, 64) ----------
__global__ __launch_bounds__(256) void k_transpose4(
    const float* __restrict__ Wq, const float* __restrict__ Wk,
    const float* __restrict__ Wv, const float* __restrict__ Wo,
    bf16_t* __restrict__ WqkvT, bf16_t* __restrict__ WoT) {
    __shared__ float tile[64][65];
    int k0 = blockIdx.x * 64;
    int n0 = blockIdx.y * 64;
    const float* W; bf16_t* WT; int np, nw;
    if (n0 < 3072) {
        W = (n0 < 1024) ? Wq : (n0 < 2048) ? Wk : Wv;
        np = n0 & 1023; WT = WqkvT; nw = n0;
    } else {
        W = Wo; np = n0 - 3072; WT = WoT; nw = n0 - 3072;
    }
    int tx = threadIdx.x & 63, ty = threadIdx.x >> 6;
    #pragma unroll
    for (int r = ty; r < 64; r += 4)
        tile[r][tx] = W[(size_t)(k0 + r) * 1024 + np + tx];
    __syncthreads();
    #pragma unroll
    for (int r = ty; r < 64; r += 4)
        WT[(size_t)(nw + r) * 1024 + k0 + tx] = f2bf(tile[tx][r]);
}

// ---------- QKV GEMM, B^T layout, global_load_lds + XOR-swizzled tiles ----------
#define BM 128
#define BN 128
#define BKK 64

__global__ __launch_bounds__(256) void k_gemm_qkv(
    const bf16_t* __restrict__ A, const bf16_t* __restrict__ BT, int K,
    const float* __restrict__ bias0, const float* __restrict__ bias1,
    const float* __restrict__ bias2,
    bf16_t* __restrict__ outQ, bf16_t* __restrict__ outK, bf16_t* __restrict__ outVt) {
    __shared__ __align__(16) bf16_t As[BM * BKK];
    __shared__ __align__(16) bf16_t Bs[BN * BKK];
    int m0 = blockIdx.x * BM;
    int n0 = blockIdx.y * BN;
    int t = threadIdx.x;
    int wid = t >> 6, lane = t & 63, l15 = lane & 15, quad = lane >> 4;
    int wr = (wid >> 1) * 64, wc = (wid & 1) * 64;
    int srow = t >> 3;
    int schunk = (t & 7) ^ (srow & 7);
    int sldst = (t & 7) * 8;
    const f32x4 fzero = {0.f, 0.f, 0.f, 0.f};
    f32x4 acc[4][4];
    #pragma unroll
    for (int i = 0; i < 4; i++)
        #pragma unroll
        for (int j = 0; j < 4; j++) acc[i][j] = fzero;

    int r7 = l15 & 7;
    for (int k0 = 0; k0 < K; k0 += BKK) {
        #pragma unroll
        for (int p = 0; p < 4; p++) {
            int r = p * 32 + srow;
            gld_lds16(&A[(size_t)(m0 + r) * K + k0 + schunk * 8], &As[r * 64 + sldst]);
            gld_lds16(&BT[(size_t)(n0 + r) * K + k0 + schunk * 8], &Bs[r * 64 + sldst]);
        }
        __syncthreads();
        #pragma unroll
        for (int kk = 0; kk < BKK; kk += 32) {
            int g = quad + (kk >> 3);
            int col = ((g ^ r7) << 3);
            bf16x8 af[4], bfr[4];
            #pragma unroll
            for (int mt = 0; mt < 4; mt++)
                af[mt] = *(const bf16x8*)&As[(wr + mt * 16 + l15) * 64 + col];
            #pragma unroll
            for (int nt = 0; nt < 4; nt++)
                bfr[nt] = *(const bf16x8*)&Bs[(wc + nt * 16 + l15) * 64 + col];
            #pragma unroll
            for (int mt = 0; mt < 4; mt++)
                #pragma unroll
                for (int nt = 0; nt < 4; nt++)
                    acc[mt][nt] = __builtin_amdgcn_mfma_f32_16x16x32_bf16(
                        af[mt], bfr[nt], acc[mt][nt], 0, 0, 0);
        }
        __syncthreads();
    }

    #pragma unroll
    for (int mt = 0; mt < 4; mt++) {
        #pragma unroll
        for (int nt = 0; nt < 4; nt++) {
            int gc = n0 + wc + nt * 16 + l15;
            int sec = gc >> 10;            // block-uniform
            int nn = gc & 1023;
            int h = nn >> 6, d = nn & 63;
            int gr0 = m0 + wr + mt * 16 + quad * 4;
            int b = gr0 >> 11, s0 = gr0 & 2047;
            if (sec == 2) {
                float bv = bias2[nn];
                uint2 pk;
                pk.x = pack2t(acc[mt][nt][0] + bv, acc[mt][nt][1] + bv);
                pk.y = pack2t(acc[mt][nt][2] + bv, acc[mt][nt][3] + bv);
                *(uint2*)&outVt[(((size_t)(b * NH + h)) * DKV + d) * S_LEN + s0] = pk;
            } else {
                const float* bias = (sec == 0) ? bias0 : bias1;
                float bv = bias[nn];
                #pragma unroll
                for (int r = 0; r < 4; r++) {
                    float val = acc[mt][nt][r] + bv;
                    size_t idx = (((size_t)(b * NH + h)) * S_LEN + s0 + r) * DKV + d;
                    if (sec == 0) outQ[idx] = f2bf(val * QSCALE);
                    else          outK[idx] = f2bf(val);
                }
            }
        }
    }
}

// ---------- out GEMM: BM=128, BN=64 (512 blocks -> 2/CU), fp32 + bias ----------
__global__ __launch_bounds__(256) void k_gemm_out(
    const bf16_t* __restrict__ A, const bf16_t* __restrict__ BT, int N, int K,
    const float* __restrict__ bias, float* __restrict__ outF) {
    __shared__ __align__(16) bf16_t As[128 * 64];
    __shared__ __align__(16) bf16_t Bs[64 * 64];
    int m0 = blockIdx.x * 128;
    int n0 = blockIdx.y * 64;
    int t = threadIdx.x;
    int wid = t >> 6, lane = t & 63, l15 = lane & 15, quad = lane >> 4;
    int wr = wid * 32;
    int srow = t >> 3;
    int schunk = (t & 7) ^ (srow & 7);
    int sldst = (t & 7) * 8;
    const f32x4 fzero = {0.f, 0.f, 0.f, 0.f};
    f32x4 acc[2][4];
    #pragma unroll
    for (int i = 0; i < 2; i++)
        #pragma unroll
        for (int j = 0; j < 4; j++) acc[i][j] = fzero;

    int r7 = l15 & 7;
    for (int k0 = 0; k0 < K; k0 += 64) {
        #pragma unroll
        for (int p = 0; p < 4; p++) {
            int r = p * 32 + srow;
            gld_lds16(&A[(size_t)(m0 + r) * K + k0 + schunk * 8], &As[r * 64 + sldst]);
        }
        #pragma unroll
        for (int p = 0; p < 2; p++) {
            int r = p * 32 + srow;
            gld_lds16(&BT[(size_t)(n0 + r) * K + k0 + schunk * 8], &Bs[r * 64 + sldst]);
        }
        __syncthreads();
        #pragma unroll
        for (int kk = 0; kk < 64; kk += 32) {
            int g = quad + (kk >> 3);
            int col = ((g ^ r7) << 3);
            bf16x8 af[2], bfr[4];
            #pragma unroll
            for (int mt = 0; mt < 2; mt++)
                af[mt] = *(const bf16x8*)&As[(wr + mt * 16 + l15) * 64 + col];
            #pragma unroll
            for (int nt = 0; nt < 4; nt++)
                bfr[nt] = *(const bf16x8*)&Bs[(nt * 16 + l15) * 64 + col];
            #pragma unroll
            for (int mt = 0; mt < 2; mt++)
                #pragma unroll
                for (int nt = 0; nt < 4; nt++)
                    acc[mt][nt] = __builtin_amdgcn_mfma_f32_16x16x32_bf16(
                        af[mt], bfr[nt], acc[mt][nt], 0, 0, 0);
        }
        __syncthreads();
    }

    #pragma unroll
    for (int mt = 0; mt < 2; mt++) {
        #pragma unroll
        for (int nt = 0; nt < 4; nt++) {
            #pragma unroll
            for (int r = 0; r < 4; r++) {
                int gr = m0 + wr + mt * 16 + quad * 4 + r;
                int gc = n0 + nt * 16 + l15;
                outF[(size_t)gr * N + gc] = acc[mt][nt][r] + bias[gc];
            }
        }
    }
}

// ---------- flash attention v9: split-k partials (flash-decoding style) ----------
// Static-base exp2 softmax => partial O_unnorm and l combine ADDITIVELY across
// k-splits. qt<16: 1 split; qt>=16: 2 splits of ceil/floor(nkt/2) (5..8 kt-iters
// each vs 9..16 unsplit). Grid 1536 near-uniform blocks (6/CU) -> refill keeps
// ~4 resident; critical path halves. LDS 40960B (4 blk/CU cap).
// Partial slot (bh*48 + slot): slot = qt (qt<16) else 16+(qt-16)*2+s.
__global__ __launch_bounds__(256) void k_attn9(
    const bf16_t* __restrict__ Q, const bf16_t* __restrict__ Kg,
    const bf16_t* __restrict__ Vt, const unsigned char* __restrict__ mask,
    bf16_t* __restrict__ Opart, float* __restrict__ lpart) {
    __shared__ __align__(16) bf16_t QPs[64 * 64];
    __shared__ __align__(16) bf16_t Ks[128 * 64];
    __shared__ __align__(16) bf16_t Vs[64 * 128];

    int bid = blockIdx.x;
    int bh = bid & 31;
    int u = bid >> 5;                  // [0,48)
    int qt, s;
    if (u < 32) { qt = 16 + (u >> 1); s = u & 1; }   // heavy halves first
    else        { qt = 47 - u;        s = 0; }       // qt 15..0
    int nkt = (qt >> 1) + 1;
    int h1 = (nkt + 1) >> 1;
    int k0i = (qt >= 16 && s == 1) ? h1 : 0;
    int kni = (qt >= 16 && s == 0) ? h1 : nkt;
    int slot = (qt < 16) ? qt : 16 + ((qt - 16) << 1) + s;
    int pidx = bh * 48 + slot;

    int b = bh >> 4;
    int t = threadIdx.x;
    int w = t >> 6, lane = t & 63, l15 = lane & 15, quad = lane >> 4;
    int r7 = l15 & 7;

    // stage Q tile (64 x 64) once into swizzled QPs, consume into registers
    const bf16_t* Qbase = Q + ((size_t)bh * S_LEN + qt * 64) * DKV;
    {
        int r = t >> 3, c8 = t & 7;
        int sc = (c8 ^ (r & 7)) * 8;
        *(uint4*)&QPs[r * 64 + sc]        = *(const uint4*)&Qbase[(size_t)r * 64 + c8 * 8];
        *(uint4*)&QPs[(r + 32) * 64 + sc] = *(const uint4*)&Qbase[(size_t)(r + 32) * 64 + c8 * 8];
    }
    __syncthreads();
    bf16x8 qf0 = *(const bf16x8*)&QPs[(w * 16 + l15) * 64 + ((quad ^ r7) << 3)];
    bf16x8 qf1 = *(const bf16x8*)&QPs[(w * 16 + l15) * 64 + (((4 + quad) ^ r7) << 3)];

    const f32x4 fzero = {0.f, 0.f, 0.f, 0.f};
    f32x4 oacc[4];
    f32x4 lacc = fzero;
    #pragma unroll
    for (int nt = 0; nt < 4; nt++) oacc[nt] = fzero;

    const bf16_t one_b = (bf16_t)1.0f;
    const bf16x8 onesf = {one_b, one_b, one_b, one_b, one_b, one_b, one_b, one_b};

    int qg   = qt * 64 + w * 16 + l15;  // lane's q column in S^T
    int qmin = qt * 64 + w * 16;
    int qmax = qmin + 15;

    // staging lane constants (dst = wave base + lane*16B by construction)
    int srK = t >> 3;
    int scK = (t & 7) ^ (srK & 7);
    int slK = (t & 7) * 8;
    int srV = t >> 4;
    int scV = (t & 15) ^ (srV & 7);
    int slV = (t & 15) * 8;

    for (int kt = k0i; kt < kni; kt++) {
        __syncthreads();
        {
            const bf16_t* Kb = Kg + ((size_t)bh * S_LEN + kt * 128) * DKV;
            #pragma unroll
            for (int p = 0; p < 4; p++) {
                int r = p * 32 + srK;
                gld_lds16(&Kb[(size_t)r * 64 + scK * 8], &Ks[r * 64 + slK]);
            }
            #pragma unroll
            for (int p = 0; p < 4; p++) {
                int r = p * 16 + srV;
                gld_lds16(&Vt[((size_t)bh * DKV + r) * S_LEN + kt * 128 + scV * 8],
                          &Vs[r * 128 + slV]);
            }
        }
        __syncthreads();

        #pragma unroll
        for (int sub = 0; sub < 2; sub++) {
            int kbase = kt * 128 + sub * 64;
            if (kbase > qmax) break;  // fully masked (wave-uniform, no barriers inside)

            // pad-mask bytes for this lane's 16 k rows
            uint32_t mb[4];
            #pragma unroll
            for (int mt = 0; mt < 4; mt++)
                mb[mt] = *(const uint32_t*)&mask[b * S_LEN + kbase + mt * 16 + quad * 4];

            // S^T subtile: row k = mt*16+quad*4+r, col q = l15
            f32x4 sacc[4];
            #pragma unroll
            for (int mt = 0; mt < 4; mt++) sacc[mt] = fzero;
            #pragma unroll
            for (int kk = 0; kk < 64; kk += 32) {
                bf16x8 qf = kk ? qf1 : qf0;
                int col = (((quad + (kk >> 3)) ^ r7) << 3);
                #pragma unroll
                for (int mt = 0; mt < 4; mt++) {
                    bf16x8 af = *(const bf16x8*)&Ks[(sub * 64 + mt * 16 + l15) * 64 + col];
                    sacc[mt] = __builtin_amdgcn_mfma_f32_16x16x32_bf16(af, qf, sacc[mt], 0, 0, 0);
                }
            }

            bool diag = (kbase + 63 > qmin);  // wave-uniform: causal mask needed?
            #pragma unroll
            for (int mt = 0; mt < 4; mt++) {
                #pragma unroll
                for (int r = 0; r < 4; r++)
                    sacc[mt][r] += (float)((mb[mt] >> (8 * r)) & 0xffu) * -1e30f;
                if (diag) {
                    int kgb = kbase + mt * 16 + quad * 4;
                    #pragma unroll
                    for (int r = 0; r < 4; r++)
                        if (kgb + r > qg) sacc[mt][r] = -1e30f;
                }
            }
            // p = exp2(s); scores O(+-6), static-base exp2 accurate (4x margin)
            #pragma unroll
            for (int mt = 0; mt < 4; mt++) {
                uint2 pk;
                pk.x = pack2t(exp2f(sacc[mt][0]), exp2f(sacc[mt][1]));
                pk.y = pack2t(exp2f(sacc[mt][2]), exp2f(sacc[mt][3]));
                int pc = (mt * 2 + (quad >> 1)) ^ r7;
                *(uint2*)&QPs[(w * 16 + l15) * 64 + pc * 8 + (quad & 1) * 4] = pk;
            }

            // O += P V; l += P * ones (row sums in same C-layout as oacc)
            #pragma unroll
            for (int kk = 0; kk < 64; kk += 32) {
                bf16x8 pf = *(const bf16x8*)&QPs[(w * 16 + l15) * 64 +
                                                 (((quad + (kk >> 3)) ^ r7) << 3)];
                int g2v = sub * 8 + (kk >> 3) + quad;
                int vcol = ((g2v ^ r7) << 3);
                #pragma unroll
                for (int nt = 0; nt < 4; nt++) {
                    bf16x8 vf = *(const bf16x8*)&Vs[(nt * 16 + l15) * 128 + vcol];
                    oacc[nt] = __builtin_amdgcn_mfma_f32_16x16x32_bf16(pf, vf, oacc[nt], 0, 0, 0);
                }
                lacc = __builtin_amdgcn_mfma_f32_16x16x32_bf16(pf, onesf, lacc, 0, 0, 0);
            }
        }
    }

    // partial epilogue: unnormalized O (bf16) + l (fp32)
    int prow = w * 16 + quad * 4;
    bf16_t* Op = Opart + (size_t)pidx * 4096;
    #pragma unroll
    for (int r = 0; r < 4; r++)
        #pragma unroll
        for (int nt = 0; nt < 4; nt++)
            Op[(prow + r) * 64 + nt * 16 + l15] = f2bf(oacc[nt][r]);
    if (l15 == 0) {
        #pragma unroll
        for (int r = 0; r < 4; r++)
            lpart[(size_t)pidx * 64 + prow + r] = lacc[r];
    }
}

// ---------- combine partials -> AOb (normalize) : grid (32 qt, 32 bh) ----------
__global__ __launch_bounds__(256) void k_combine(
    const bf16_t* __restrict__ Opart, const float* __restrict__ lpart,
    bf16_t* __restrict__ AO) {
    __shared__ float linv[64];
    int qt = blockIdx.x, bh = blockIdx.y;
    int b = bh >> 4, h = bh & 15;
    int nsp = (qt < 16) ? 1 : 2;
    int slot0 = (qt < 16) ? qt : 16 + ((qt - 16) << 1);
    size_t p0 = (size_t)(bh * 48 + slot0);
    int t = threadIdx.x;
    if (t < 64) {
        float l = lpart[p0 * 64 + t];
        if (nsp == 2) l += lpart[(p0 + 1) * 64 + t];
        linv[t] = (l > 0.f) ? 1.f / l : 0.f;
    }
    __syncthreads();
    int row = t >> 2, c0 = (t & 3) * 16;
    const uint16_t* s0p = (const uint16_t*)Opart + p0 * 4096 + row * 64 + c0;
    float v[16];
    #pragma unroll
    for (int j = 0; j < 16; j++) {
        union { uint32_t u; float f; } cv; cv.u = (uint32_t)s0p[j] << 16;
        v[j] = cv.f;
    }
    if (nsp == 2) {
        #pragma unroll
        for (int j = 0; j < 16; j++) {
            union { uint32_t u; float f; } cv; cv.u = (uint32_t)s0p[4096 + j] << 16;
            v[j] += cv.f;
        }
    }
    float invl = linv[row];
    union { uint16_t sv[16]; uint4 u[2]; } pk;
    #pragma unroll
    for (int j = 0; j < 16; j++) pk.sv[j] = f2bfu(v[j] * invl);
    bf16_t* dst = AO + ((size_t)b * S_LEN + qt * 64 + row) * D_MODEL + h * DKV + c0;
    *(uint4*)dst = pk.u[0];
    *(uint4*)(dst + 8) = pk.u[1];
}

extern "C" void kernel_launch(void* const* d_in, const int* in_sizes, int n_in,
                              void* d_out, int out_size, void* d_ws, size_t ws_size,
                              hipStream_t stream) {
    const float* x = (const float*)d_in[0];
    const unsigned char* mask = (const unsigned char*)d_in[1];
    const float* Wq = (const float*)d_in[2];
    const float* bq = (const float*)d_in[3];
    const float* Wk = (const float*)d_in[4];
    const float* bk = (const float*)d_in[5];
    const float* Wv = (const float*)d_in[6];
    const float* bv = (const float*)d_in[7];
    const float* Wo = (const float*)d_in[8];
    const float* bo = (const float*)d_in[9];
    float* out = (float*)d_out;

    char* ws = (char*)d_ws;
    const size_t MB = 1024 * 1024;
    // Max ws footprint: 48 MB. Partials overlap xb+WqkvT (dead after k_gemm_qkv):
    // Opart 12.6MB at [0,12.6), lpart 0.4MB at [13,13.4) -- both < 14MB zone.
    bf16_t* xb    = (bf16_t*)(ws + 0 * MB);   // 8 MB (dead after qkv gemm)
    bf16_t* Opart = (bf16_t*)(ws + 0 * MB);   // 12.6 MB partial O (1536 x 64 x 64 bf16)
    float*  lpart = (float*) (ws + 13 * MB);  // 384 KB partial l (1536 x 64 fp32)
    bf16_t* WqkvT = (bf16_t*)(ws + 8 * MB);   // 6 MB (dead after qkv gemm)
    bf16_t* WoT   = (bf16_t*)(ws + 14 * MB);  // 2 MB
    bf16_t* Qb    = (bf16_t*)(ws + 16 * MB);  // 8 MB [bh][s][64], pre-scaled QSCALE
    bf16_t* Kb    = (bf16_t*)(ws + 24 * MB);  // 8 MB [bh][s][64]
    bf16_t* Vtb   = (bf16_t*)(ws + 32 * MB);  // 8 MB V^T [bh][64][2048]
    bf16_t* AOb   = (bf16_t*)(ws + 40 * MB);  // 8 MB attn out [4096,1024]

    k_convert_x<<<dim3(4096), dim3(256), 0, stream>>>(x, xb, 4 * 1024 * 1024);
    k_transpose4<<<dim3(16, 64), dim3(256), 0, stream>>>(Wq, Wk, Wv, Wo, WqkvT, WoT);
    k_gemm_qkv<<<dim3(32, 24), dim3(256), 0, stream>>>(
        xb, WqkvT, 1024, bq, bk, bv, Qb, Kb, Vtb);
    k_attn9<<<dim3(1536), dim3(256), 0, stream>>>(Qb, Kb, Vtb, mask, Opart, lpart);
    k_combine<<<dim3(32, 32), dim3(256), 0, stream>>>(Opart, lpart, AOb);
    k_gemm_out<<<dim3(32, 16), dim3(256), 0, stream>>>(
        AOb, WoT, 1024, 1024, bo, out);
}

// Round 13
// 192.449 us; speedup vs baseline: 1.0063x; 1.0063x over previous
//
#include <hip/hip_runtime.h>
#include <stdint.h>

typedef __bf16 bf16_t;
typedef __bf16 bf16x8 __attribute__((ext_vector_type(8)));
typedef float f32x4 __attribute__((ext_vector_type(4)));

#define S_LEN 2048
#define D_MODEL 1024
#define NH 16
#define DKV 64
#define BATCH 2

// 0.125 (1/sqrt(64)) * log2(e): Q pre-scale so softmax runs in exp2 domain.
#define QSCALE 0.1803368801111204f

__device__ __forceinline__ uint16_t f2bfu(float f) {
    union { float f; uint32_t u; } c; c.f = f;
    return (uint16_t)((c.u + 0x7fffu + ((c.u >> 16) & 1u)) >> 16);
}
__device__ __forceinline__ bf16_t f2bf(float f) {
    union { uint16_t s; bf16_t b; } o; o.s = f2bfu(f);
    return o.b;
}
// truncation pack via v_perm: result = (lo>>16) | (hi & 0xFFFF0000)
__device__ __forceinline__ uint32_t pack2t(float lo, float hi) {
    union { float f; uint32_t u; } a, b; a.f = lo; b.f = hi;
    return __builtin_amdgcn_perm(b.u, a.u, 0x07060302);
}
// async global->LDS 16B DMA (dst = wave-uniform base + lane*16)
__device__ __forceinline__ void gld_lds16(const bf16_t* g, bf16_t* l) {
    __builtin_amdgcn_global_load_lds(
        (const __attribute__((address_space(1))) void*)g,
        (__attribute__((address_space(3))) void*)l, 16, 0, 0);
}

// ---------- fused prep (1D grid 1280, block-uniform branch) ----------
// bid < 1024 : weight transpose (bx = bid&15 -> k0, by = bid>>4 -> n0 over 4096)
//              by 0..47: Wq|Wk|Wv -> WqkvT ; by 48..63: Wo -> WoT
// bid >= 1024: x -> bf16 convert, 256 blocks x 16 float4-iters each.
__global__ __launch_bounds__(256) void k_prep2(
    const float* __restrict__ x, bf16_t* __restrict__ xb,
    const float* __restrict__ Wq, const float* __restrict__ Wk,
    const float* __restrict__ Wv, const float* __restrict__ Wo,
    bf16_t* __restrict__ WqkvT, bf16_t* __restrict__ WoT) {
    __shared__ float tile[64][65];
    int bid = blockIdx.x;
    int t = threadIdx.x;
    if (bid >= 1024) {
        int cid = bid - 1024;
        #pragma unroll
        for (int j = 0; j < 16; j++) {
            int i = cid * 16384 + (j * 256 + t) * 4;
            float4 v = *(const float4*)(x + i);
            xb[i + 0] = f2bf(v.x);
            xb[i + 1] = f2bf(v.y);
            xb[i + 2] = f2bf(v.z);
            xb[i + 3] = f2bf(v.w);
        }
        return;
    }
    int k0 = (bid & 15) * 64;
    int n0 = (bid >> 4) * 64;
    const float* W; bf16_t* WT; int np, nw;
    if (n0 < 3072) {
        W = (n0 < 1024) ? Wq : (n0 < 2048) ? Wk : Wv;
        np = n0 & 1023; WT = WqkvT; nw = n0;
    } else {
        W = Wo; np = n0 - 3072; WT = WoT; nw = n0 - 3072;
    }
    int tx = t & 63, ty = t >> 6;
    #pragma unroll
    for (int r = ty; r < 64; r += 4)
        tile[r][tx] = W[(size_t)(k0 + r) * 1024 + np + tx];
    __syncthreads();
    #pragma unroll
    for (int r = ty; r < 64; r += 4)
        WT[(size_t)(nw + r) * 1024 + k0 + tx] = f2bf(tile[tx][r]);
}

// ---------- QKV GEMM, B^T layout, global_load_lds + XOR-swizzled tiles ----------
#define BM 128
#define BN 128
#define BKK 64

__global__ __launch_bounds__(256) void k_gemm_qkv(
    const bf16_t* __restrict__ A, const bf16_t* __restrict__ BT, int K,
    const float* __restrict__ bias0, const float* __restrict__ bias1,
    const float* __restrict__ bias2,
    bf16_t* __restrict__ outQ, bf16_t* __restrict__ outK, bf16_t* __restrict__ outVt) {
    __shared__ __align__(16) bf16_t As[BM * BKK];
    __shared__ __align__(16) bf16_t Bs[BN * BKK];
    int m0 = blockIdx.x * BM;
    int n0 = blockIdx.y * BN;
    int t = threadIdx.x;
    int wid = t >> 6, lane = t & 63, l15 = lane & 15, quad = lane >> 4;
    int wr = (wid >> 1) * 64, wc = (wid & 1) * 64;
    int srow = t >> 3;
    int schunk = (t & 7) ^ (srow & 7);
    int sldst = (t & 7) * 8;
    const f32x4 fzero = {0.f, 0.f, 0.f, 0.f};
    f32x4 acc[4][4];
    #pragma unroll
    for (int i = 0; i < 4; i++)
        #pragma unroll
        for (int j = 0; j < 4; j++) acc[i][j] = fzero;

    int r7 = l15 & 7;
    for (int k0 = 0; k0 < K; k0 += BKK) {
        #pragma unroll
        for (int p = 0; p < 4; p++) {
            int r = p * 32 + srow;
            gld_lds16(&A[(size_t)(m0 + r) * K + k0 + schunk * 8], &As[r * 64 + sldst]);
            gld_lds16(&BT[(size_t)(n0 + r) * K + k0 + schunk * 8], &Bs[r * 64 + sldst]);
        }
        __syncthreads();
        #pragma unroll
        for (int kk = 0; kk < BKK; kk += 32) {
            int g = quad + (kk >> 3);
            int col = ((g ^ r7) << 3);
            bf16x8 af[4], bfr[4];
            #pragma unroll
            for (int mt = 0; mt < 4; mt++)
                af[mt] = *(const bf16x8*)&As[(wr + mt * 16 + l15) * 64 + col];
            #pragma unroll
            for (int nt = 0; nt < 4; nt++)
                bfr[nt] = *(const bf16x8*)&Bs[(wc + nt * 16 + l15) * 64 + col];
            #pragma unroll
            for (int mt = 0; mt < 4; mt++)
                #pragma unroll
                for (int nt = 0; nt < 4; nt++)
                    acc[mt][nt] = __builtin_amdgcn_mfma_f32_16x16x32_bf16(
                        af[mt], bfr[nt], acc[mt][nt], 0, 0, 0);
        }
        __syncthreads();
    }

    #pragma unroll
    for (int mt = 0; mt < 4; mt++) {
        #pragma unroll
        for (int nt = 0; nt < 4; nt++) {
            int gc = n0 + wc + nt * 16 + l15;
            int sec = gc >> 10;            // block-uniform
            int nn = gc & 1023;
            int h = nn >> 6, d = nn & 63;
            int gr0 = m0 + wr + mt * 16 + quad * 4;
            int b = gr0 >> 11, s0 = gr0 & 2047;
            if (sec == 2) {
                float bv = bias2[nn];
                uint2 pk;
                pk.x = pack2t(acc[mt][nt][0] + bv, acc[mt][nt][1] + bv);
                pk.y = pack2t(acc[mt][nt][2] + bv, acc[mt][nt][3] + bv);
                *(uint2*)&outVt[(((size_t)(b * NH + h)) * DKV + d) * S_LEN + s0] = pk;
            } else {
                const float* bias = (sec == 0) ? bias0 : bias1;
                float bv = bias[nn];
                #pragma unroll
                for (int r = 0; r < 4; r++) {
                    float val = acc[mt][nt][r] + bv;
                    size_t idx = (((size_t)(b * NH + h)) * S_LEN + s0 + r) * DKV + d;
                    if (sec == 0) outQ[idx] = f2bf(val * QSCALE);
                    else          outK[idx] = f2bf(val);
                }
            }
        }
    }
}

// ---------- out GEMM: BM=128, BN=32 -> grid(32,32)=1024 blocks (4/CU) ----------
// LDS: As 16KB + Bs 4KB = 20KB. Wave w covers rows w*32..+31, cols 0..31.
__global__ __launch_bounds__(256) void k_gemm_out(
    const bf16_t* __restrict__ A, const bf16_t* __restrict__ BT, int N, int K,
    const float* __restrict__ bias, float* __restrict__ outF) {
    __shared__ __align__(16) bf16_t As[128 * 64];
    __shared__ __align__(16) bf16_t Bs[32 * 64];
    int m0 = blockIdx.x * 128;
    int n0 = blockIdx.y * 32;
    int t = threadIdx.x;
    int wid = t >> 6, lane = t & 63, l15 = lane & 15, quad = lane >> 4;
    int wr = wid * 32;
    int srow = t >> 3;
    int schunk = (t & 7) ^ (srow & 7);
    int sldst = (t & 7) * 8;
    const f32x4 fzero = {0.f, 0.f, 0.f, 0.f};
    f32x4 acc[2][2];
    #pragma unroll
    for (int i = 0; i < 2; i++)
        #pragma unroll
        for (int j = 0; j < 2; j++) acc[i][j] = fzero;

    int r7 = l15 & 7;
    for (int k0 = 0; k0 < K; k0 += 64) {
        #pragma unroll
        for (int p = 0; p < 4; p++) {
            int r = p * 32 + srow;
            gld_lds16(&A[(size_t)(m0 + r) * K + k0 + schunk * 8], &As[r * 64 + sldst]);
        }
        gld_lds16(&BT[(size_t)(n0 + srow) * K + k0 + schunk * 8], &Bs[srow * 64 + sldst]);
        __syncthreads();
        #pragma unroll
        for (int kk = 0; kk < 64; kk += 32) {
            int g = quad + (kk >> 3);
            int col = ((g ^ r7) << 3);
            bf16x8 af[2], bfr[2];
            #pragma unroll
            for (int mt = 0; mt < 2; mt++)
                af[mt] = *(const bf16x8*)&As[(wr + mt * 16 + l15) * 64 + col];
            #pragma unroll
            for (int nt = 0; nt < 2; nt++)
                bfr[nt] = *(const bf16x8*)&Bs[(nt * 16 + l15) * 64 + col];
            #pragma unroll
            for (int mt = 0; mt < 2; mt++)
                #pragma unroll
                for (int nt = 0; nt < 2; nt++)
                    acc[mt][nt] = __builtin_amdgcn_mfma_f32_16x16x32_bf16(
                        af[mt], bfr[nt], acc[mt][nt], 0, 0, 0);
        }
        __syncthreads();
    }

    #pragma unroll
    for (int mt = 0; mt < 2; mt++) {
        #pragma unroll
        for (int nt = 0; nt < 2; nt++) {
            #pragma unroll
            for (int r = 0; r < 4; r++) {
                int gr = m0 + wr + mt * 16 + quad * 4 + r;
                int gc = n0 + nt * 16 + l15;
                outF[(size_t)gr * N + gc] = acc[mt][nt][r] + bias[gc];
            }
        }
    }
}

// ---------- flash attention v8 (R11-proven): 40960B LDS, gld_lds, XOR-swizzle ----------
__global__ __launch_bounds__(256) void k_attn8(
    const bf16_t* __restrict__ Q, const bf16_t* __restrict__ Kg,
    const bf16_t* __restrict__ Vt, const unsigned char* __restrict__ mask,
    bf16_t* __restrict__ O) {
    __shared__ __align__(16) bf16_t QPs[64 * 64];
    __shared__ __align__(16) bf16_t Ks[128 * 64];
    __shared__ __align__(16) bf16_t Vs[64 * 128];

    int bid = blockIdx.x;
    int bh = bid & 31;
    int u = bid >> 5;
    int a = u & 7, g2 = u >> 3;
    int qt = (g2 == 0) ? 31 - a : (g2 == 1) ? a : (g2 == 2) ? 23 - a : 8 + a;
    int b = bh >> 4, h = bh & 15;
    int t = threadIdx.x;
    int w = t >> 6, lane = t & 63, l15 = lane & 15, quad = lane >> 4;
    int r7 = l15 & 7;

    // stage Q tile (64 x 64) once into swizzled QPs, consume into registers
    const bf16_t* Qbase = Q + ((size_t)bh * S_LEN + qt * 64) * DKV;
    {
        int r = t >> 3, c8 = t & 7;
        int sc = (c8 ^ (r & 7)) * 8;
        *(uint4*)&QPs[r * 64 + sc]        = *(const uint4*)&Qbase[(size_t)r * 64 + c8 * 8];
        *(uint4*)&QPs[(r + 32) * 64 + sc] = *(const uint4*)&Qbase[(size_t)(r + 32) * 64 + c8 * 8];
    }
    __syncthreads();
    bf16x8 qf0 = *(const bf16x8*)&QPs[(w * 16 + l15) * 64 + ((quad ^ r7) << 3)];
    bf16x8 qf1 = *(const bf16x8*)&QPs[(w * 16 + l15) * 64 + (((4 + quad) ^ r7) << 3)];

    const f32x4 fzero = {0.f, 0.f, 0.f, 0.f};
    f32x4 oacc[4];
    f32x4 lacc = fzero;
    #pragma unroll
    for (int nt = 0; nt < 4; nt++) oacc[nt] = fzero;

    const bf16_t one_b = (bf16_t)1.0f;
    const bf16x8 onesf = {one_b, one_b, one_b, one_b, one_b, one_b, one_b, one_b};

    int qg   = qt * 64 + w * 16 + l15;  // lane's q column in S^T
    int qmin = qt * 64 + w * 16;
    int qmax = qmin + 15;
    int ktmax = qt >> 1;

    // staging lane constants (dst = wave base + lane*16B by construction)
    int srK = t >> 3;
    int scK = (t & 7) ^ (srK & 7);
    int slK = (t & 7) * 8;
    int srV = t >> 4;
    int scV = (t & 15) ^ (srV & 7);
    int slV = (t & 15) * 8;

    for (int kt = 0; kt <= ktmax; kt++) {
        __syncthreads();
        {
            const bf16_t* Kb = Kg + ((size_t)bh * S_LEN + kt * 128) * DKV;
            #pragma unroll
            for (int p = 0; p < 4; p++) {
                int r = p * 32 + srK;
                gld_lds16(&Kb[(size_t)r * 64 + scK * 8], &Ks[r * 64 + slK]);
            }
            #pragma unroll
            for (int p = 0; p < 4; p++) {
                int r = p * 16 + srV;
                gld_lds16(&Vt[((size_t)bh * DKV + r) * S_LEN + kt * 128 + scV * 8],
                          &Vs[r * 128 + slV]);
            }
        }
        __syncthreads();

        #pragma unroll
        for (int sub = 0; sub < 2; sub++) {
            int kbase = kt * 128 + sub * 64;
            if (kbase > qmax) break;  // fully masked (wave-uniform, no barriers inside)

            // pad-mask bytes for this lane's 16 k rows
            uint32_t mb[4];
            #pragma unroll
            for (int mt = 0; mt < 4; mt++)
                mb[mt] = *(const uint32_t*)&mask[b * S_LEN + kbase + mt * 16 + quad * 4];

            // S^T subtile: row k = mt*16+quad*4+r, col q = l15
            f32x4 sacc[4];
            #pragma unroll
            for (int mt = 0; mt < 4; mt++) sacc[mt] = fzero;
            #pragma unroll
            for (int kk = 0; kk < 64; kk += 32) {
                bf16x8 qf = kk ? qf1 : qf0;
                int col = (((quad + (kk >> 3)) ^ r7) << 3);
                #pragma unroll
                for (int mt = 0; mt < 4; mt++) {
                    bf16x8 af = *(const bf16x8*)&Ks[(sub * 64 + mt * 16 + l15) * 64 + col];
                    sacc[mt] = __builtin_amdgcn_mfma_f32_16x16x32_bf16(af, qf, sacc[mt], 0, 0, 0);
                }
            }

            bool diag = (kbase + 63 > qmin);  // wave-uniform: causal mask needed?
            #pragma unroll
            for (int mt = 0; mt < 4; mt++) {
                #pragma unroll
                for (int r = 0; r < 4; r++)
                    sacc[mt][r] += (float)((mb[mt] >> (8 * r)) & 0xffu) * -1e30f;
                if (diag) {
                    int kgb = kbase + mt * 16 + quad * 4;
                    #pragma unroll
                    for (int r = 0; r < 4; r++)
                        if (kgb + r > qg) sacc[mt][r] = -1e30f;
                }
            }
            // p = exp2(s); scores O(+-6), static-base exp2 accurate (4x margin)
            #pragma unroll
            for (int mt = 0; mt < 4; mt++) {
                uint2 pk;
                pk.x = pack2t(exp2f(sacc[mt][0]), exp2f(sacc[mt][1]));
                pk.y = pack2t(exp2f(sacc[mt][2]), exp2f(sacc[mt][3]));
                int pc = (mt * 2 + (quad >> 1)) ^ r7;
                *(uint2*)&QPs[(w * 16 + l15) * 64 + pc * 8 + (quad & 1) * 4] = pk;
            }

            // O += P V; l += P * ones (row sums in same C-layout as oacc)
            #pragma unroll
            for (int kk = 0; kk < 64; kk += 32) {
                bf16x8 pf = *(const bf16x8*)&QPs[(w * 16 + l15) * 64 +
                                                 (((quad + (kk >> 3)) ^ r7) << 3)];
                int g2v = sub * 8 + (kk >> 3) + quad;
                int vcol = ((g2v ^ r7) << 3);
                #pragma unroll
                for (int nt = 0; nt < 4; nt++) {
                    bf16x8 vf = *(const bf16x8*)&Vs[(nt * 16 + l15) * 128 + vcol];
                    oacc[nt] = __builtin_amdgcn_mfma_f32_16x16x32_bf16(pf, vf, oacc[nt], 0, 0, 0);
                }
                lacc = __builtin_amdgcn_mfma_f32_16x16x32_bf16(pf, onesf, lacc, 0, 0, 0);
            }
        }
    }

    #pragma unroll
    for (int r = 0; r < 4; r++) {
        float l = lacc[r];
        float invl = l > 0.f ? 1.f / l : 0.f;
        int q = qt * 64 + w * 16 + quad * 4 + r;
        #pragma unroll
        for (int nt = 0; nt < 4; nt++) {
            int d = nt * 16 + l15;
            O[((size_t)b * S_LEN + q) * D_MODEL + h * DKV + d] = f2bf(oacc[nt][r] * invl);
        }
    }
}

extern "C" void kernel_launch(void* const* d_in, const int* in_sizes, int n_in,
                              void* d_out, int out_size, void* d_ws, size_t ws_size,
                              hipStream_t stream) {
    const float* x = (const float*)d_in[0];
    const unsigned char* mask = (const unsigned char*)d_in[1];
    const float* Wq = (const float*)d_in[2];
    const float* bq = (const float*)d_in[3];
    const float* Wk = (const float*)d_in[4];
    const float* bk = (const float*)d_in[5];
    const float* Wv = (const float*)d_in[6];
    const float* bv = (const float*)d_in[7];
    const float* Wo = (const float*)d_in[8];
    const float* bo = (const float*)d_in[9];
    float* out = (float*)d_out;

    char* ws = (char*)d_ws;
    const size_t MB = 1024 * 1024;
    // Max ws footprint: 48 MB.
    bf16_t* xb    = (bf16_t*)(ws + 0 * MB);   // 8 MB
    bf16_t* WqkvT = (bf16_t*)(ws + 8 * MB);   // 6 MB
    bf16_t* WoT   = (bf16_t*)(ws + 14 * MB);  // 2 MB
    bf16_t* Qb    = (bf16_t*)(ws + 16 * MB);  // 8 MB [bh][s][64], pre-scaled QSCALE
    bf16_t* Kb    = (bf16_t*)(ws + 24 * MB);  // 8 MB [bh][s][64]
    bf16_t* Vtb   = (bf16_t*)(ws + 32 * MB);  // 8 MB V^T [bh][64][2048]
    bf16_t* AOb   = (bf16_t*)(ws + 40 * MB);  // 8 MB attn out [4096,1024]

    k_prep2<<<dim3(1280), dim3(256), 0, stream>>>(x, xb, Wq, Wk, Wv, Wo, WqkvT, WoT);
    k_gemm_qkv<<<dim3(32, 24), dim3(256), 0, stream>>>(
        xb, WqkvT, 1024, bq, bk, bv, Qb, Kb, Vtb);
    k_attn8<<<dim3(1024), dim3(256), 0, stream>>>(Qb, Kb, Vtb, mask, AOb);
    k_gemm_out<<<dim3(32, 32), dim3(256), 0, stream>>>(
        AOb, WoT, 1024, 1024, bo, out);
}